// Round 4
// baseline (390.889 us; speedup 1.0000x reference)
//
#include <hip/hip_runtime.h>
#include <stdint.h>
#include <stddef.h>

// ---------------------------------------------------------------------------
// WQLinear: out[M][N] = x[M][K] * W[N][K]^T + bias
//   M=4096, K=4096, N=11008; W = int4 AWQ dequant (group 128)
// Pass 1: dequant W -> bf16 ws in MFMA-FRAGMENT-PACKED layout; x -> bf16 ws
//   (row-major). Fragment (n16=n/16, kc=k/32) = 1 KiB at (n16*128+kc)*1024;
//   byte lane*16 holds W[n16*16 + (lane&15)][kc*32 + (lane>>4)*8 .. +7].
// Pass 2: 256x256x64 8-wave MFMA GEMM (128x64 wave tiles, 16x16x32 MFMA).
//   B operand: DIRECT global->VGPR fragment loads (no LDS for B at all).
//   A operand: LDS-staged via global_load_lds as before (reused 4x across wn).
//   LDS datapath/K-tile: 256KB-equiv -> 160KB (A reads 128K + writes 32K);
//   MFMA pipe (2483 cyc/CU/K-tile) becomes critical.
//   Phase order Q00(a0b0), Q10(a1b0), Q01(a0b1), Q11(a1b1):
//     b0 last use ph1 -> reload B0(t+1) at ph1 end (lands by ph0(t+1), 2-phase
//     margin); b1 last use ph3 -> reload B1(t+1) at ph3 end (lands ph2(t+1)).
//   VMEM queue/tile: ph0:[glA0] ph1:[glA1,B0x4] ph2:[glA2] ph3:[glA3,B1x4]
//   Waits (conservative intra-phase ordering): ph0 vmcnt(6) [B0(t)+As1(t)],
//   ph2 vmcnt(6) [B1(t)], ph3 vmcnt(13) [As0(t+1); structurally a no-op].
//   Barriers: ph0 + ph2 only (restage-vs-last-read legality verified:
//   glA0/glA1 write As0(t+2) after ph0 barrier > all waves' ph3(t-1) a0(t)
//   drains; glA2/glA3 write As1(t+2) after ph2 barrier > all waves' ph0(t)
//   a1(t) drains).
// ---------------------------------------------------------------------------

#define M_DIM 4096
#define N_DIM 11008
#define K_DIM 4096
#define NT    (K_DIM / 64)          // 64 K-tiles

typedef __bf16 bf16x8 __attribute__((ext_vector_type(8)));
typedef float f32x4 __attribute__((ext_vector_type(4)));
typedef unsigned int u32x4 __attribute__((ext_vector_type(4)));
typedef unsigned short u16x8 __attribute__((ext_vector_type(8)));
typedef unsigned short u16x4 __attribute__((ext_vector_type(4)));

__device__ __forceinline__ unsigned short f2bf(float f) {
    unsigned int u = __float_as_uint(f);
    u += 0x7fffu + ((u >> 16) & 1u);   // round-to-nearest-even
    return (unsigned short)(u >> 16);
}

typedef const __attribute__((address_space(1))) void* as1_cptr;
typedef __attribute__((address_space(3))) void* as3_ptr;

__device__ __forceinline__ void gl_lds16(const void* g, void* l) {
    __builtin_amdgcn_global_load_lds((as1_cptr)g, (as3_ptr)l, 16, 0, 0);
}

#define MFMA16(A, B, C) __builtin_amdgcn_mfma_f32_16x16x32_bf16((A), (B), (C), 0, 0, 0)

// ---- pre-kernel 1: dequant W (int4 -> bf16, FRAGMENT-PACKED layout) ----
// One thread per (fragment, lane): writes 16 contiguous bytes; wave writes one
// full 1 KiB fragment contiguously (perfect store coalescing).
__global__ __launch_bounds__(256)
void dequant_w_kernel(const int* __restrict__ qw, const int* __restrict__ qz,
                      const float* __restrict__ sc, unsigned short* __restrict__ Wbf)
{
    int idx  = blockIdx.x * 256 + threadIdx.x;   // (frag, lane)
    int lane = idx & 63;
    int frag = idx >> 6;                         // 0 .. 88063
    int n16  = frag >> 7;                        // n / 16
    int kc   = frag & 127;                       // k / 32
    int n    = n16 * 16 + (lane & 15);
    int k0   = kc * 32 + ((lane >> 4) << 3);     // 8 consecutive k
    int g    = k0 >> 7;                          // quant group
    unsigned int zw = (unsigned int)qz[n * 4 + (g >> 3)];
    float z = (float)((zw >> ((g & 7) * 4)) & 15u);
    float s = sc[n * 32 + g];
    float nz = -z * s;
    unsigned int w = (unsigned int)qw[n * 512 + (k0 >> 3)];
    u16x8 t;
#pragma unroll
    for (int j = 0; j < 8; ++j) {
        float q = (float)((w >> (4 * j)) & 15u);
        t[j] = f2bf(__builtin_fmaf(q, s, nz));
    }
    *(u16x8*)(Wbf + (size_t)idx * 8) = t;        // frag*1024B + lane*16B
}

// ---- pre-kernel 2: x fp32 -> bf16 row-major [M][K] ----
__global__ __launch_bounds__(256)
void conv_x_kernel(const float* __restrict__ x, unsigned short* __restrict__ Xbf)
{
    size_t i8 = ((size_t)blockIdx.x * 256 + threadIdx.x) * 8;
    f32x4 a = *(const f32x4*)(x + i8);
    f32x4 b = *(const f32x4*)(x + i8 + 4);
    u16x8 t;
#pragma unroll
    for (int j = 0; j < 4; ++j) t[j] = f2bf(a[j]);
#pragma unroll
    for (int j = 0; j < 4; ++j) t[4 + j] = f2bf(b[j]);
    *(u16x8*)(Xbf + i8) = t;
}

// ---- main GEMM: 256x256 tile, BK=64, 8 waves (2x4), B direct-from-global ----
#define LDA_RD(BASE, MHc, fmc, kkc) \
    __builtin_bit_cast(bf16x8, *(const u32x4*)((BASE) + (MHc)*16384 + (fmc)*2048 + a_rd + (swz ^ ((kkc)*64))))
#define LDB_G(IDX, OFF, kkc) \
    __builtin_bit_cast(bf16x8, *(const u32x4*)(pB[IDX] + (OFF) + (kkc)*1024))

__global__ __launch_bounds__(512, 2)
void gemm256_kernel(const unsigned short* __restrict__ Xbf,
                    const unsigned short* __restrict__ Wbf,
                    const float* __restrict__ bias,
                    float* __restrict__ out)
{
    __shared__ u32x4 lds4[4096];            // 64 KiB: A only, [2 buf][256 rows][128 B]
    char* ldsA = (char*)lds4;

    const int tid = threadIdx.x;
    const int lane = tid & 63, wid = tid >> 6;
    const int l16 = lane & 15, g4 = lane >> 4;
    const int wm = wid >> 2, wn = wid & 3;

    // XCD-aware bijective swizzle: 688 blocks = 8 XCD x 86; per XCD 2x43
    // rectangle walked column-major.
    const int bid = blockIdx.x;
    const int xcd = bid & 7, c = bid >> 3;
    const int tm = 2 * xcd + (c & 1), tn = c >> 1;
    const int m0 = tm * 256, n0 = tn * 256;

    const int swz  = (g4 ^ (l16 & 7)) << 4;            // read-side XOR (bytes)
    const int a_rd = (wm * 64 + l16) * 128;
    // inverse-swizzled per-lane global offset (linear LDS dst, swizzled src)
    const size_t goff = (size_t)(lane >> 3) * 8192 + (size_t)(((lane & 7) ^ (lane >> 3)) << 4);

    const char* pAg = (const char*)Xbf + (size_t)m0 * 8192 + goff;
    const size_t rowA = (size_t)(wid * 8) * 8192;       // rows 0-63 (8/wave)
    const size_t rowB = (size_t)((wid + 8) * 8) * 8192; // rows 64-127
    const int ldst0 = wid * 1024, ldst1 = (wid + 8) * 1024;

    // B fragment base pointers: idx = NH*2+fn -> n16 = n0/16 + NH*8 + wn*2 + fn
    const char* pB[4];
#pragma unroll
    for (int NH = 0; NH < 2; ++NH)
#pragma unroll
        for (int fn = 0; fn < 2; ++fn) {
            int n16v = (n0 >> 4) + NH * 8 + wn * 2 + fn;
            pB[NH * 2 + fn] = (const char*)Wbf + (size_t)n16v * 131072 + (size_t)lane * 16;
        }

    f32x4 acc[8][4];
#pragma unroll
    for (int i = 0; i < 8; ++i)
#pragma unroll
        for (int j = 0; j < 4; ++j) acc[i][j] = f32x4{0.f, 0.f, 0.f, 0.f};

    float bvv[4];
#pragma unroll
    for (int q = 0; q < 4; ++q)
        bvv[q] = bias[n0 + (q >> 1) * 128 + wn * 32 + (q & 1) * 16 + l16];

    bf16x8 a0[4][2], a1[4][2], b0[2][2], b1[2][2];

    // ---- prologue (queue mirrors steady state; 16 VMEM ops) ----
    // As0(0), As1(0):
    gl_lds16(pAg + rowA, ldsA + ldst0);                         // op1  glA0(0)
    gl_lds16(pAg + rowB, ldsA + ldst1);                         // op2  glA1(0)
    gl_lds16(pAg + 1048576 + rowA, ldsA + 16384 + ldst0);       // op3  glA2(0)
    gl_lds16(pAg + 1048576 + rowB, ldsA + 16384 + ldst1);       // op4  glA3(0)
    // wu(-1) steady-shaped: As0(1); B0(0); As1(1); B1(0)
    gl_lds16(pAg + 128 + rowA, ldsA + 32768 + ldst0);           // op5  glA0(1)
    gl_lds16(pAg + 128 + rowB, ldsA + 32768 + ldst1);           // op6  glA1(1)
#pragma unroll
    for (int fn = 0; fn < 2; ++fn)
#pragma unroll
        for (int kk = 0; kk < 2; ++kk)
            b0[fn][kk] = LDB_G(fn, 0, kk);                      // op7-10 B0(0)
    gl_lds16(pAg + 1048576 + 128 + rowA, ldsA + 49152 + ldst0); // op11 glA2(1)
    gl_lds16(pAg + 1048576 + 128 + rowB, ldsA + 49152 + ldst1); // op12 glA3(1)
#pragma unroll
    for (int fn = 0; fn < 2; ++fn)
#pragma unroll
        for (int kk = 0; kk < 2; ++kk)
            b1[fn][kk] = LDB_G(2 + fn, 0, kk);                  // op13-16 B1(0)

    // pre-read a0(0): needs As0(0) = ops 1,2 -> allow newest 14
    asm volatile("s_waitcnt vmcnt(14)" ::: "memory");
    __builtin_amdgcn_s_barrier();
    asm volatile("" ::: "memory");
#pragma unroll
    for (int fm = 0; fm < 4; ++fm) {
        a0[fm][0] = LDA_RD(ldsA, 0, fm, 0);
        a0[fm][1] = LDA_RD(ldsA, 0, fm, 1);
    }
    asm volatile("s_waitcnt lgkmcnt(0)" ::: "memory");
    __builtin_amdgcn_sched_barrier(0);

#pragma unroll 2
    for (int t = 0; t < NT; ++t) {
        const int p = t & 1;
        char* Ap = ldsA + p * 32768;
        char* An = ldsA + (p ^ 1) * 32768;
        const size_t k2 = (size_t)((t + 2 < NT ? t + 2 : NT - 1) * 128);
        const size_t kb = (size_t)((t + 1 < NT ? t + 1 : NT - 1) * 2048);

        // == ph0: Q00 = a0*b0 ; ds_read a1(t) ; stage glA0 = As0(t+2) l0 ==
        // vmcnt(6): forces B0(t) [ph1(t-1)] and As1(t) [ph2/ph3(t-2)]
        asm volatile("s_waitcnt vmcnt(6)" ::: "memory");
        __builtin_amdgcn_s_barrier();
        asm volatile("" ::: "memory");
        gl_lds16(pAg + rowA + k2, Ap + ldst0);
#pragma unroll
        for (int fm = 0; fm < 4; ++fm) {
            a1[fm][0] = LDA_RD(Ap, 1, fm, 0);
            a1[fm][1] = LDA_RD(Ap, 1, fm, 1);
        }
        __builtin_amdgcn_s_setprio(1);
#pragma unroll
        for (int fm = 0; fm < 4; ++fm)
#pragma unroll
            for (int fn = 0; fn < 2; ++fn) {
                acc[fm][fn] = MFMA16(a0[fm][0], b0[fn][0], acc[fm][fn]);
                acc[fm][fn] = MFMA16(a0[fm][1], b0[fn][1], acc[fm][fn]);
            }
        __builtin_amdgcn_s_setprio(0);
        asm volatile("s_waitcnt lgkmcnt(0)" ::: "memory");
        __builtin_amdgcn_sched_barrier(0);

        // == ph1: Q10 = a1*b0 ; stage glA1 = As0(t+2) l1 ; reload B0(t+1) ==
        gl_lds16(pAg + rowB + k2, Ap + ldst1);
        __builtin_amdgcn_s_setprio(1);
#pragma unroll
        for (int fm = 0; fm < 4; ++fm)
#pragma unroll
            for (int fn = 0; fn < 2; ++fn) {
                acc[4 + fm][fn] = MFMA16(a1[fm][0], b0[fn][0], acc[4 + fm][fn]);
                acc[4 + fm][fn] = MFMA16(a1[fm][1], b0[fn][1], acc[4 + fm][fn]);
            }
        __builtin_amdgcn_s_setprio(0);
#pragma unroll
        for (int fn = 0; fn < 2; ++fn)
#pragma unroll
            for (int kk = 0; kk < 2; ++kk)
                b0[fn][kk] = LDB_G(fn, kb, kk);
        asm volatile("s_waitcnt lgkmcnt(0)" ::: "memory");
        __builtin_amdgcn_sched_barrier(0);

        // == ph2: Q01 = a0*b1 ; stage glA2 = As1(t+2) l0 ==
        // vmcnt(6): forces B1(t) [ph3(t-1)]
        asm volatile("s_waitcnt vmcnt(6)" ::: "memory");
        __builtin_amdgcn_s_barrier();
        asm volatile("" ::: "memory");
        gl_lds16(pAg + 1048576 + rowA + k2, Ap + 16384 + ldst0);
        __builtin_amdgcn_s_setprio(1);
#pragma unroll
        for (int fm = 0; fm < 4; ++fm)
#pragma unroll
            for (int fn = 0; fn < 2; ++fn) {
                acc[fm][2 + fn] = MFMA16(a0[fm][0], b1[fn][0], acc[fm][2 + fn]);
                acc[fm][2 + fn] = MFMA16(a0[fm][1], b1[fn][1], acc[fm][2 + fn]);
            }
        __builtin_amdgcn_s_setprio(0);
        asm volatile("s_waitcnt lgkmcnt(0)" ::: "memory");
        __builtin_amdgcn_sched_barrier(0);

        // == ph3: Q11 = a1*b1 ; ds_read a0(t+1) ; stage glA3 = As1(t+2) l1 ;
        //         reload B1(t+1) ==
        // vmcnt(13): guard for As0(t+1) [glA0/glA1(t-1)]; structurally no-op
        asm volatile("s_waitcnt vmcnt(13)" ::: "memory");
        gl_lds16(pAg + 1048576 + rowB + k2, Ap + 16384 + ldst1);
#pragma unroll
        for (int fm = 0; fm < 4; ++fm) {
            a0[fm][0] = LDA_RD(An, 0, fm, 0);
            a0[fm][1] = LDA_RD(An, 0, fm, 1);
        }
        __builtin_amdgcn_s_setprio(1);
#pragma unroll
        for (int fm = 0; fm < 4; ++fm)
#pragma unroll
            for (int fn = 0; fn < 2; ++fn) {
                acc[4 + fm][2 + fn] = MFMA16(a1[fm][0], b1[fn][0], acc[4 + fm][2 + fn]);
                acc[4 + fm][2 + fn] = MFMA16(a1[fm][1], b1[fn][1], acc[4 + fm][2 + fn]);
            }
        __builtin_amdgcn_s_setprio(0);
#pragma unroll
        for (int fn = 0; fn < 2; ++fn)
#pragma unroll
            for (int kk = 0; kk < 2; ++kk)
                b1[fn][kk] = LDB_G(2 + fn, kb, kk);
        asm volatile("s_waitcnt lgkmcnt(0)" ::: "memory");
        __builtin_amdgcn_sched_barrier(0);
    }

    asm volatile("s_waitcnt vmcnt(0)" ::: "memory");   // drain dummy restages

    // epilogue: C/D layout col=lane&15, row=(lane>>4)*4+reg
#pragma unroll
    for (int MH = 0; MH < 2; ++MH)
#pragma unroll
        for (int fm = 0; fm < 4; ++fm) {
            size_t r0 = (size_t)(m0 + MH * 128 + wm * 64 + fm * 16 + g4 * 4);
#pragma unroll
            for (int NH = 0; NH < 2; ++NH)
#pragma unroll
                for (int fn = 0; fn < 2; ++fn) {
                    int col = n0 + NH * 128 + wn * 32 + fn * 16 + l16;
                    f32x4 v = acc[MH * 4 + fm][NH * 2 + fn];
                    float bb = bvv[NH * 2 + fn];
#pragma unroll
                    for (int r = 0; r < 4; ++r)
                        out[(r0 + r) * N_DIM + col] = v[r] + bb;
                }
        }
}

// ---- fallback (no-ws): round-1 fused-dequant 128^2 kernel (verified) ----
__global__ __launch_bounds__(256, 2)
void gemm_fallback(const float* __restrict__ x,
                   const int* __restrict__ qweight,
                   const int* __restrict__ qzeros,
                   const float* __restrict__ scales,
                   const float* __restrict__ bias,
                   float* __restrict__ out)
{
    __shared__ u32x4 lds_raw[2048];
    char* ldsA = (char*)lds_raw;
    char* ldsB = ldsA + 16384;

    const int tid = threadIdx.x;
    const int n0 = blockIdx.x * 128;
    const int m0 = blockIdx.y * 128;
    const int wave = tid >> 6;
    const int lane = tid & 63;
    const int l16 = lane & 15;
    const int g4 = lane >> 4;
    const int wm = wave >> 1;
    const int wn = wave & 1;

    f32x4 acc[4][4];
#pragma unroll
    for (int i = 0; i < 4; ++i)
#pragma unroll
        for (int j = 0; j < 4; ++j) acc[i][j] = f32x4{0.f, 0.f, 0.f, 0.f};

    for (int kt = 0; kt < K_DIM / 64; ++kt) {
        __syncthreads();
#pragma unroll
        for (int i = 0; i < 4; ++i) {
            int cI = tid + i * 256;
            int row = cI >> 4, cc = cI & 15;
            f32x4 v = *(const f32x4*)(x + ((size_t)(m0 + row) * K_DIM + kt * 64 + cc * 4));
            u16x4 h;
#pragma unroll
            for (int j = 0; j < 4; ++j) h[j] = f2bf(v[j]);
            int b = row * 128 + cc * 8;
            *(u16x4*)(ldsA + (b ^ ((row & 7) << 4))) = h;
        }
        {
            int row = tid >> 1, half = tid & 1;
            int n = n0 + row;
            int g = kt >> 1;
            unsigned int zw = (unsigned int)qzeros[n * 4 + (g >> 3)];
            float z = (float)((zw >> ((g & 7) * 4)) & 15u);
            float s = scales[n * 32 + g];
            float nz = -z * s;
            u32x4 w4 = *(const u32x4*)(qweight + (size_t)n * 512 + kt * 8 + half * 4);
#pragma unroll
            for (int j4 = 0; j4 < 4; ++j4) {
                unsigned int w = w4[j4];
                u16x8 tt;
#pragma unroll
                for (int j = 0; j < 8; ++j) {
                    float q = (float)((w >> (4 * j)) & 15u);
                    tt[j] = f2bf(__builtin_fmaf(q, s, nz));
                }
                int b = row * 128 + half * 64 + j4 * 16;
                *(u16x8*)(ldsB + (b ^ ((row & 7) << 4))) = tt;
            }
        }
        __syncthreads();

#pragma unroll
        for (int kk = 0; kk < 2; ++kk) {
            bf16x8 af[4], bfm[4];
#pragma unroll
            for (int fm = 0; fm < 4; ++fm) {
                int arow = wm * 64 + fm * 16 + l16;
                int ab = arow * 128 + kk * 64 + g4 * 16;
                af[fm] = __builtin_bit_cast(bf16x8, *(const u32x4*)(ldsA + (ab ^ ((arow & 7) << 4))));
            }
#pragma unroll
            for (int fn = 0; fn < 4; ++fn) {
                int brow = wn * 64 + fn * 16 + l16;
                int bb = brow * 128 + kk * 64 + g4 * 16;
                bfm[fn] = __builtin_bit_cast(bf16x8, *(const u32x4*)(ldsB + (bb ^ ((brow & 7) << 4))));
            }
#pragma unroll
            for (int fm = 0; fm < 4; ++fm)
#pragma unroll
                for (int fn = 0; fn < 4; ++fn)
                    acc[fm][fn] = MFMA16(af[fm], bfm[fn], acc[fm][fn]);
        }
    }

#pragma unroll
    for (int fm = 0; fm < 4; ++fm) {
        int row0 = m0 + wm * 64 + fm * 16 + g4 * 4;
#pragma unroll
        for (int fn = 0; fn < 4; ++fn) {
            int col = n0 + wn * 64 + fn * 16 + l16;
            float bv = bias[col];
            f32x4 a = acc[fm][fn];
#pragma unroll
            for (int r = 0; r < 4; ++r)
                out[(size_t)(row0 + r) * N_DIM + col] = a[r] + bv;
        }
    }
}

extern "C" void kernel_launch(void* const* d_in, const int* in_sizes, int n_in,
                              void* d_out, int out_size, void* d_ws, size_t ws_size,
                              hipStream_t stream)
{
    const float* x      = (const float*)d_in[0];
    const int* qweight  = (const int*)d_in[1];
    const int* qzeros   = (const int*)d_in[2];
    const float* scales = (const float*)d_in[3];
    const float* bias   = (const float*)d_in[4];
    float* out          = (float*)d_out;

    const size_t WB = (size_t)N_DIM * K_DIM * 2;
    const size_t XB = (size_t)M_DIM * K_DIM * 2;

    if (ws_size >= WB + XB) {
        unsigned short* Wbf = (unsigned short*)d_ws;
        unsigned short* Xbf = (unsigned short*)((char*)d_ws + WB);
        dequant_w_kernel<<<dim3(22016), dim3(256), 0, stream>>>(qweight, qzeros, scales, Wbf);
        conv_x_kernel<<<dim3(8192), dim3(256), 0, stream>>>(x, Xbf);
        gemm256_kernel<<<dim3(688), dim3(512), 0, stream>>>(Xbf, Wbf, bias, out);
    } else {
        dim3 grid(N_DIM / 128, M_DIM / 128);
        gemm_fallback<<<grid, dim3(256), 0, stream>>>(x, qweight, qzeros, scales, bias, out);
    }
}